// Round 3
// baseline (149.147 us; speedup 1.0000x reference)
//
#include <hip/hip_runtime.h>
#include <hip/hip_fp16.h>
#include <math.h>

#define NN 1024

typedef _Float16 half8 __attribute__((ext_vector_type(8)));
typedef float f32x4 __attribute__((ext_vector_type(4)));

union H8U { uint4 u; half8 h; };

__device__ __forceinline__ unsigned short h_bits(float x) {
    _Float16 h = (_Float16)x;          // RNE
    unsigned short b;
    __builtin_memcpy(&b, &h, 2);
    return b;
}

// ---- prep: blocks [0,512): A' = z_c@W1c + b1 -> fp16 frag-order Aph;
//            B = z_d@W1d -> fp16 frag-order Bph.
//            blocks [512,514): W2 -> fp16 MFMA frag layout W2h.
__global__ void prep_kernel(const float* __restrict__ z_c, const float* __restrict__ z_d,
                            const float* __restrict__ W1, const float* __restrict__ b1,
                            const float* __restrict__ W2,
                            unsigned short* __restrict__ Aph,
                            unsigned short* __restrict__ Bph,
                            uint4* __restrict__ W2h) {
    if (blockIdx.x < 512) {
        int t = blockIdx.x * 256 + threadIdx.x;
        int sel = t >> 16;            // 0 -> A', 1 -> B
        int idx = t & 0xffff;
        int n = idx >> 6, h = idx & 63;
        const float* z = (sel ? z_d : z_c) + n * 64;
        const float* w = W1 + (sel ? 4096 : 0) + h;   // W1 (128,64) row-major
        float a0 = sel ? 0.f : b1[h], a1 = 0.f;
        #pragma unroll
        for (int k = 0; k < 64; k += 2) {
            a0 = fmaf(z[k],     w[k * 64],       a0);
            a1 = fmaf(z[k + 1], w[(k + 1) * 64], a1);
        }
        unsigned short val = h_bits(a0 + a1);   // fp32-exact matmul, one RNE to fp16
        int s = h >> 5, q = (h >> 3) & 3, e = h & 7;
        if (sel) {
            Bph[n * 64 + q * 16 + s * 8 + e] = val;
        } else {
            Aph[(n >> 4) * 1024 + (q * 16 + (n & 15)) * 16 + s * 8 + e] = val;
        }
    } else {
        int tt = (blockIdx.x - 512) * 256 + threadIdx.x;   // 0..511
        int f = tt >> 6, lane = tt & 63;                   // f = s*4 + t, 8 frags
        int s = f >> 2, t4 = f & 3, q = lane >> 4, l15 = lane & 15;
        int n = t4 * 16 + l15;
        unsigned w4[4];
        #pragma unroll
        for (int p = 0; p < 4; ++p) {
            int k = s * 32 + q * 8 + 2 * p;
            unsigned lo = h_bits(W2[k * 64 + n]);
            unsigned hi = h_bits(W2[(k + 1) * 64 + n]);
            w4[p] = lo | (hi << 16);
        }
        W2h[f * 64 + lane] = make_uint4(w4[0], w4[1], w4[2], w4[3]);
    }
}

// ---- main: 512 blocks x 256 thr; block b owns ROWS i0=2b and i0+1 (ROW-PAIRING,
// R3 probe): each Aph tile load (x0/x1) is reused for BOTH rows' relu-add + MFMA,
// halving main's dominant traffic term (134 MB -> 67 MB of L2->L1 Aph streaming)
// and doubling arithmetic intensity. Rows are processed SEQUENTIALLY per tile
// (acc[4] reused) to keep the live set under the 128-VGPR budget of
// __launch_bounds__(256, 4). Row math is bit-identical to the single-row version.
// Whole rows in one block: plain stores, ZERO atomics anywhere.
// R1 POST-MORTEM (do not reintroduce): grid-scale same-address atomicAdd ->
// serialized cross-XCD coherence drain, +5us steady net of a saved launch.
// R2: cold-main 126us/Occ 1.1% appears with AND without atomics -> profiling
// artifact; judge by steady dur_us only.
__global__ void __launch_bounds__(256, 4)
main_kernel(const unsigned short* __restrict__ Aph, const unsigned short* __restrict__ Bph,
            const uint4* __restrict__ W2h,
            const float* __restrict__ b2, const float* __restrict__ Wo,
            float* __restrict__ Crow) {
    const int i0   = blockIdx.x << 1;
    const int tid  = threadIdx.x;
    const int lane = tid & 63;
    const int wave = tid >> 6;
    const int l15  = lane & 15;
    const int q    = lane >> 4;

    __shared__ uint4 sW[512];      // W2 frag bits, 8 KB
    __shared__ float sb2[64];      // b2, 256 B
    __shared__ float sWo[64];      // Wo, 256 B
    __shared__ float sS[4][2];     // per-wave exp-sum partials, per row
    __shared__ float sT0[2];       // diagonal T1[i,i] per row

    // cooperative stage: 2 x 16B VMEM per thread + tiny b2/Wo copy
    sW[tid]       = W2h[tid];
    sW[tid + 256] = W2h[tid + 256];
    if (tid < 64)                  sb2[tid]      = b2[tid];
    else if (tid < 128)            sWo[tid - 64] = Wo[tid - 64];
    __syncthreads();

    // W2 fragments from LDS: 8 ds_read_b128, lane-contiguous (conflict-free)
    half8 W[2][4];   // [s][t]
    #pragma unroll
    for (int f = 0; f < 8; ++f) {
        H8U u; u.u = sW[f * 64 + lane];
        W[f >> 2][f & 3] = u.h;
    }

    // B slices for both rows (fp16 frag order): 4 dwordx4
    H8U cbA0, cbA1, cbB0, cbB1;
    {
        const uint4* bpA = (const uint4*)(Bph + i0 * 64 + q * 16);
        cbA0.u = bpA[0];
        cbA1.u = bpA[1];
        const uint4* bpB = (const uint4*)(Bph + (i0 + 1) * 64 + q * 16);
        cbB0.u = bpB[0];
        cbB1.u = bpB[1];
    }

    // b2 folded into acc init; Wo per-lane, element (t,r) is h = t*16 + q*4 + r
    f32x4 b2v[4];
    float wov[4][4];
    #pragma unroll
    for (int t = 0; t < 4; ++t) {
        float4 bt = *(const float4*)(sb2 + t * 16 + q * 4);
        float4 wt = *(const float4*)(sWo + t * 16 + q * 4);
        b2v[t] = (f32x4){bt.x, bt.y, bt.z, bt.w};
        wov[t][0] = wt.x; wov[t][1] = wt.y; wov[t][2] = wt.z; wov[t][3] = wt.w;
    }

    const half8 zero = {0, 0, 0, 0, 0, 0, 0, 0};
    float saccA = 0.f, saccB = 0.f;

    // Two groups of 8 tiles; psum pairs reused per group -> bounded registers.
    #pragma unroll
    for (int g = 0; g < 2; ++g) {
        const int tbase = wave * 16 + g * 8;
        const unsigned short* ap = Aph + tbase * 1024 + lane * 16;

        H8U x0, x1;
        x0.u = ((const uint4*)ap)[0];
        x1.u = ((const uint4*)ap)[1];

        float psumA[8], psumB[8];

        #pragma unroll
        for (int tile = 0; tile < 8; ++tile) {
            // both rows' h1 slices from ONE x load
            half8 a0 = __builtin_elementwise_max(x0.h + cbA0.h, zero);   // row A, k 0..31
            half8 a1 = __builtin_elementwise_max(x1.h + cbA1.h, zero);   // row A, k 32..63
            half8 c0 = __builtin_elementwise_max(x0.h + cbB0.h, zero);   // row B
            half8 c1 = __builtin_elementwise_max(x1.h + cbB1.h, zero);
            if (tile < 7) {
                const uint4* nx = (const uint4*)(ap + (tile + 1) * 1024);
                x0.u = nx[0];
                x1.u = nx[1];
            }

            f32x4 acc[4];

            // ---- row A
            #pragma unroll
            for (int t = 0; t < 4; ++t) acc[t] = b2v[t];
            #pragma unroll
            for (int t = 0; t < 4; ++t) {
                acc[t] = __builtin_amdgcn_mfma_f32_16x16x32_f16(W[0][t], a0, acc[t], 0, 0, 0);
                acc[t] = __builtin_amdgcn_mfma_f32_16x16x32_f16(W[1][t], a1, acc[t], 0, 0, 0);
            }
            {
                float p0 = 0.f, p1 = 0.f, p2 = 0.f, p3 = 0.f;
                #pragma unroll
                for (int t = 0; t < 4; ++t) {
                    p0 = fmaf(fmaxf(acc[t][0], 0.f), wov[t][0], p0);
                    p1 = fmaf(fmaxf(acc[t][1], 0.f), wov[t][1], p1);
                    p2 = fmaf(fmaxf(acc[t][2], 0.f), wov[t][2], p2);
                    p3 = fmaf(fmaxf(acc[t][3], 0.f), wov[t][3], p3);
                }
                psumA[tile] = (p0 + p1) + (p2 + p3);
            }

            // ---- row B (same x, different B-add)
            #pragma unroll
            for (int t = 0; t < 4; ++t) acc[t] = b2v[t];
            #pragma unroll
            for (int t = 0; t < 4; ++t) {
                acc[t] = __builtin_amdgcn_mfma_f32_16x16x32_f16(W[0][t], c0, acc[t], 0, 0, 0);
                acc[t] = __builtin_amdgcn_mfma_f32_16x16x32_f16(W[1][t], c1, acc[t], 0, 0, 0);
            }
            {
                float p0 = 0.f, p1 = 0.f, p2 = 0.f, p3 = 0.f;
                #pragma unroll
                for (int t = 0; t < 4; ++t) {
                    p0 = fmaf(fmaxf(acc[t][0], 0.f), wov[t][0], p0);
                    p1 = fmaf(fmaxf(acc[t][1], 0.f), wov[t][1], p1);
                    p2 = fmaf(fmaxf(acc[t][2], 0.f), wov[t][2], p2);
                    p3 = fmaf(fmaxf(acc[t][3], 0.f), wov[t][3], p3);
                }
                psumB[tile] = (p0 + p1) + (p2 + p3);
            }
        }

        // Epilogue for this group: independent reduce/exp chains per row
        #pragma unroll
        for (int tile = 0; tile < 8; ++tile) {
            const int j = (tbase + tile) * 16 + l15;

            float ps = psumA[tile];
            ps += __shfl_xor(ps, 16);
            ps += __shfl_xor(ps, 32);   // T1[i0, j], replicated over 4 q-groups
            if (j == i0 && q == 0) sT0[0] = ps;
            saccA += __expf(ps);

            float pt = psumB[tile];
            pt += __shfl_xor(pt, 16);
            pt += __shfl_xor(pt, 32);   // T1[i0+1, j]
            if (j == i0 + 1 && q == 0) sT0[1] = pt;
            saccB += __expf(pt);
        }
    }

    // reduce over l15 only (q-groups are exact replicas -> exact sum)
    #pragma unroll
    for (int off = 1; off < 16; off <<= 1) {
        saccA += __shfl_xor(saccA, off);
        saccB += __shfl_xor(saccB, off);
    }
    if (lane == 0) { sS[wave][0] = saccA; sS[wave][1] = saccB; }
    __syncthreads();
    if (tid == 0) {
        float SA = (sS[0][0] + sS[1][0]) + (sS[2][0] + sS[3][0]);
        float SB = (sS[0][1] + sS[1][1]) + (sS[2][1] + sS[3][1]);
        Crow[i0]     = sT0[0] - logf(SA);   // per-row logf: 1024-way parallel
        Crow[i0 + 1] = sT0[1] - logf(SB);
    }
}

// ---- combine: 1 block x 1024 thr. bound = mean(Crow) + ln N
__global__ void __launch_bounds__(1024)
combine_finish(const float* __restrict__ Crow, float* __restrict__ out) {
    float c = Crow[threadIdx.x];
    #pragma unroll
    for (int off = 1; off < 64; off <<= 1) c += __shfl_xor(c, off);
    __shared__ float sc[16];
    int w = threadIdx.x >> 6;
    if ((threadIdx.x & 63) == 0) sc[w] = c;
    __syncthreads();
    if (threadIdx.x == 0) {
        float C = 0.f;
        #pragma unroll
        for (int k = 0; k < 16; ++k) C += sc[k];
        out[0] = C * (1.0f / 1024.0f) + 6.9314718055994531f;   // + ln 1024
    }
}

extern "C" void kernel_launch(void* const* d_in, const int* in_sizes, int n_in,
                              void* d_out, int out_size, void* d_ws, size_t ws_size,
                              hipStream_t stream) {
    const float* z_c = (const float*)d_in[0];
    const float* z_d = (const float*)d_in[1];
    const float* W1  = (const float*)d_in[2];
    const float* b1  = (const float*)d_in[3];
    const float* W2  = (const float*)d_in[4];
    const float* b2  = (const float*)d_in[5];
    const float* Wo  = (const float*)d_in[6];
    // d_in[7] = bo: shifts T0.mean and every LSE equally -> cancels; omitted.
    float* out   = (float*)d_out;

    unsigned short* Aph = (unsigned short*)d_ws;   // 65536 fp16 (128 KB), frag-order
    unsigned short* Bph = Aph + NN * 64;           // 65536 fp16 (128 KB), frag-order
    uint4* W2h   = (uint4*)(Bph + NN * 64);        // 512 uint4 (8 KB)
    float* Crow  = (float*)(W2h + 512);            // 1024 fp32 (plain-stored by main)

    prep_kernel<<<514, 256, 0, stream>>>(z_c, z_d, W1, b1, W2, Aph, Bph, W2h);
    main_kernel<<<512, 256, 0, stream>>>(Aph, Bph, W2h, b2, Wo, Crow);
    combine_finish<<<1, 1024, 0, stream>>>(Crow, out);
}

// Round 5
// 86.550 us; speedup vs baseline: 1.7232x; 1.7232x over previous
//
#include <hip/hip_runtime.h>
#include <hip/hip_fp16.h>
#include <math.h>

#define NN 1024

typedef _Float16 half8 __attribute__((ext_vector_type(8)));
typedef float f32x4 __attribute__((ext_vector_type(4)));

union H8U { uint4 u; half8 h; };

__device__ __forceinline__ unsigned short h_bits(float x) {
    _Float16 h = (_Float16)x;          // RNE
    unsigned short b;
    __builtin_memcpy(&b, &h, 2);
    return b;
}

// ---- prep: blocks [0,512): A' = z_c@W1c + b1 -> fp16 frag-order Aph;
//            B = z_d@W1d -> fp16 frag-order Bph.
//            blocks [512,514): W2 -> fp16 MFMA frag layout W2h.
__global__ void prep_kernel(const float* __restrict__ z_c, const float* __restrict__ z_d,
                            const float* __restrict__ W1, const float* __restrict__ b1,
                            const float* __restrict__ W2,
                            unsigned short* __restrict__ Aph,
                            unsigned short* __restrict__ Bph,
                            uint4* __restrict__ W2h) {
    if (blockIdx.x < 512) {
        int t = blockIdx.x * 256 + threadIdx.x;
        int sel = t >> 16;            // 0 -> A', 1 -> B
        int idx = t & 0xffff;
        int n = idx >> 6, h = idx & 63;
        const float* z = (sel ? z_d : z_c) + n * 64;
        const float* w = W1 + (sel ? 4096 : 0) + h;   // W1 (128,64) row-major
        float a0 = sel ? 0.f : b1[h], a1 = 0.f;
        #pragma unroll
        for (int k = 0; k < 64; k += 2) {
            a0 = fmaf(z[k],     w[k * 64],       a0);
            a1 = fmaf(z[k + 1], w[(k + 1) * 64], a1);
        }
        unsigned short val = h_bits(a0 + a1);   // fp32-exact matmul, one RNE to fp16
        int s = h >> 5, q = (h >> 3) & 3, e = h & 7;
        if (sel) {
            Bph[n * 64 + q * 16 + s * 8 + e] = val;
        } else {
            Aph[(n >> 4) * 1024 + (q * 16 + (n & 15)) * 16 + s * 8 + e] = val;
        }
    } else {
        int tt = (blockIdx.x - 512) * 256 + threadIdx.x;   // 0..511
        int f = tt >> 6, lane = tt & 63;                   // f = s*4 + t, 8 frags
        int s = f >> 2, t4 = f & 3, q = lane >> 4, l15 = lane & 15;
        int n = t4 * 16 + l15;
        unsigned w4[4];
        #pragma unroll
        for (int p = 0; p < 4; ++p) {
            int k = s * 32 + q * 8 + 2 * p;
            unsigned lo = h_bits(W2[k * 64 + n]);
            unsigned hi = h_bits(W2[(k + 1) * 64 + n]);
            w4[p] = lo | (hi << 16);
        }
        W2h[f * 64 + lane] = make_uint4(w4[0], w4[1], w4[2], w4[3]);
    }
}

// ---- main: 1024 blocks x 256 thr; block = row i, each wave 16 j-tiles of 16.
// R5: DEPTH-2 REGISTER PIPELINE. R1/R2 cold-profile back-solve showed main steady
// ~19us at VALUBusy~13% / MfmaUtil~5% -- latency-stalled, not throughput-bound
// (cross-XCD Aph reads via L3 ~500cy; old 1-tile-ahead prefetch covers ~175cy).
// Fix: single 16-tile loop, ping-pong prefetch pairs xa/xb (2 tiles ahead), and
// the per-tile epilogue (shfl/exp) inlined so psum[8] disappears. Register
// ledger: old {x 8 + psum 8} == new {xa 8 + xb 8} -> exactly neutral vs the
// measured (102,128] footprint. Tile order and all op order bit-identical.
// R3 POST-MORTEM stands: any state growth spills (325MB scratch, 80.7us steady).
// R4 POST-MORTEM: hipLaunchCooperativeKernel fails SILENTLY under the harness's
// graph capture (out==0 -> absmax=|ref|=3.2e-2). Cooperative launch is BANNED.
// R1 POST-MORTEM stands: grid-scale same-address atomicAdd is poison (+5us net).
// __launch_bounds__(256, 4) is LOAD-BEARING. Do not raise.
__global__ void __launch_bounds__(256, 4)
main_kernel(const unsigned short* __restrict__ Aph, const unsigned short* __restrict__ Bph,
            const uint4* __restrict__ W2h,
            const float* __restrict__ b2, const float* __restrict__ Wo,
            float* __restrict__ Crow) {
    const int i    = blockIdx.x;
    const int tid  = threadIdx.x;
    const int lane = tid & 63;
    const int wave = tid >> 6;
    const int l15  = lane & 15;
    const int q    = lane >> 4;

    __shared__ uint4 sW[512];      // W2 frag bits, 8 KB
    __shared__ float sb2[64];      // b2, 256 B
    __shared__ float sWo[64];      // Wo, 256 B
    __shared__ float sS[4];        // per-wave exp-sum partials
    __shared__ float sT0;          // diagonal T1[i,i] = T0[i]

    // cooperative stage: 2 x 16B VMEM per thread + tiny b2/Wo copy
    sW[tid]       = W2h[tid];
    sW[tid + 256] = W2h[tid + 256];
    if (tid < 64)                  sb2[tid]      = b2[tid];
    else if (tid < 128)            sWo[tid - 64] = Wo[tid - 64];
    __syncthreads();

    // W2 fragments from LDS: 8 ds_read_b128, lane-contiguous (conflict-free)
    half8 W[2][4];   // [s][t]
    #pragma unroll
    for (int f = 0; f < 8; ++f) {
        H8U u; u.u = sW[f * 64 + lane];
        W[f >> 2][f & 3] = u.h;
    }

    // B_i per-lane slice (fp16 frag order): 2 dwordx4 = 16 halves, k = s*32+q*8+e
    H8U cb0, cb1;
    {
        const uint4* bp = (const uint4*)(Bph + i * 64 + q * 16);
        cb0.u = bp[0];
        cb1.u = bp[1];
    }

    // b2 folded into acc init; Wo per-lane, element (t,r) is h = t*16 + q*4 + r
    f32x4 b2v[4];
    float wov[4][4];
    #pragma unroll
    for (int t = 0; t < 4; ++t) {
        float4 bt = *(const float4*)(sb2 + t * 16 + q * 4);
        float4 wt = *(const float4*)(sWo + t * 16 + q * 4);
        b2v[t] = (f32x4){bt.x, bt.y, bt.z, bt.w};
        wov[t][0] = wt.x; wov[t][1] = wt.y; wov[t][2] = wt.z; wov[t][3] = wt.w;
    }

    const half8 zero = {0, 0, 0, 0, 0, 0, 0, 0};
    float sacc = 0.f;

    // Wave's 16 tiles, contiguous: tile T at Aph + (wave*16+T)*1024 + lane*16.
    const unsigned short* ap = Aph + (wave * 16) * 1024 + lane * 16;

    // Prologue: tiles 0 and 1 in flight.
    H8U xa0, xa1, xb0, xb1;
    xa0.u = ((const uint4*)ap)[0];
    xa1.u = ((const uint4*)ap)[1];
    {
        const uint4* p1 = (const uint4*)(ap + 1024);
        xb0.u = p1[0];
        xb1.u = p1[1];
    }

    #pragma unroll
    for (int t = 0; t < 16; t += 2) {
        // ---- even tile t: consume xa, refill xa with tile t+2
        {
            half8 a0 = __builtin_elementwise_max(xa0.h + cb0.h, zero);   // k 0..31
            half8 a1 = __builtin_elementwise_max(xa1.h + cb1.h, zero);   // k 32..63
            if (t + 2 < 16) {
                const uint4* nx = (const uint4*)(ap + (t + 2) * 1024);
                xa0.u = nx[0];
                xa1.u = nx[1];
            }

            f32x4 acc[4];
            #pragma unroll
            for (int u = 0; u < 4; ++u) acc[u] = b2v[u];
            #pragma unroll
            for (int u = 0; u < 4; ++u) {
                acc[u] = __builtin_amdgcn_mfma_f32_16x16x32_f16(W[0][u], a0, acc[u], 0, 0, 0);
                acc[u] = __builtin_amdgcn_mfma_f32_16x16x32_f16(W[1][u], a1, acc[u], 0, 0, 0);
            }

            float p0 = 0.f, p1 = 0.f, p2 = 0.f, p3 = 0.f;
            #pragma unroll
            for (int u = 0; u < 4; ++u) {
                p0 = fmaf(fmaxf(acc[u][0], 0.f), wov[u][0], p0);
                p1 = fmaf(fmaxf(acc[u][1], 0.f), wov[u][1], p1);
                p2 = fmaf(fmaxf(acc[u][2], 0.f), wov[u][2], p2);
                p3 = fmaf(fmaxf(acc[u][3], 0.f), wov[u][3], p3);
            }
            float ps = (p0 + p1) + (p2 + p3);
            ps += __shfl_xor(ps, 16);
            ps += __shfl_xor(ps, 32);   // T1[j], replicated over the 4 q-groups
            const int j = (wave * 16 + t) * 16 + l15;
            if (j == i && q == 0) sT0 = ps;   // diagonal: exactly one writer
            sacc += __expf(ps);
        }
        // ---- odd tile t+1: consume xb, refill xb with tile t+3
        {
            half8 a0 = __builtin_elementwise_max(xb0.h + cb0.h, zero);
            half8 a1 = __builtin_elementwise_max(xb1.h + cb1.h, zero);
            if (t + 3 < 16) {
                const uint4* nx = (const uint4*)(ap + (t + 3) * 1024);
                xb0.u = nx[0];
                xb1.u = nx[1];
            }

            f32x4 acc[4];
            #pragma unroll
            for (int u = 0; u < 4; ++u) acc[u] = b2v[u];
            #pragma unroll
            for (int u = 0; u < 4; ++u) {
                acc[u] = __builtin_amdgcn_mfma_f32_16x16x32_f16(W[0][u], a0, acc[u], 0, 0, 0);
                acc[u] = __builtin_amdgcn_mfma_f32_16x16x32_f16(W[1][u], a1, acc[u], 0, 0, 0);
            }

            float p0 = 0.f, p1 = 0.f, p2 = 0.f, p3 = 0.f;
            #pragma unroll
            for (int u = 0; u < 4; ++u) {
                p0 = fmaf(fmaxf(acc[u][0], 0.f), wov[u][0], p0);
                p1 = fmaf(fmaxf(acc[u][1], 0.f), wov[u][1], p1);
                p2 = fmaf(fmaxf(acc[u][2], 0.f), wov[u][2], p2);
                p3 = fmaf(fmaxf(acc[u][3], 0.f), wov[u][3], p3);
            }
            float ps = (p0 + p1) + (p2 + p3);
            ps += __shfl_xor(ps, 16);
            ps += __shfl_xor(ps, 32);
            const int j = (wave * 16 + t + 1) * 16 + l15;
            if (j == i && q == 0) sT0 = ps;
            sacc += __expf(ps);
        }
    }

    // reduce over l15 only (q-groups are exact replicas -> exact sum)
    sacc += __shfl_xor(sacc, 1);
    sacc += __shfl_xor(sacc, 2);
    sacc += __shfl_xor(sacc, 4);
    sacc += __shfl_xor(sacc, 8);
    if (lane == 0) sS[wave] = sacc;
    __syncthreads();
    if (tid == 0) {
        float S = (sS[0] + sS[1]) + (sS[2] + sS[3]);   // whole row in this block
        Crow[i] = sT0 - logf(S);   // per-row logf: 1024-way parallel
    }
}

// ---- combine: 1 block x 1024 thr. bound = mean(Crow) + ln N
__global__ void __launch_bounds__(1024)
combine_finish(const float* __restrict__ Crow, float* __restrict__ out) {
    float c = Crow[threadIdx.x];
    #pragma unroll
    for (int off = 1; off < 64; off <<= 1) c += __shfl_xor(c, off);
    __shared__ float sc[16];
    int w = threadIdx.x >> 6;
    if ((threadIdx.x & 63) == 0) sc[w] = c;
    __syncthreads();
    if (threadIdx.x == 0) {
        float C = 0.f;
        #pragma unroll
        for (int k = 0; k < 16; ++k) C += sc[k];
        out[0] = C * (1.0f / 1024.0f) + 6.9314718055994531f;   // + ln 1024
    }
}

extern "C" void kernel_launch(void* const* d_in, const int* in_sizes, int n_in,
                              void* d_out, int out_size, void* d_ws, size_t ws_size,
                              hipStream_t stream) {
    const float* z_c = (const float*)d_in[0];
    const float* z_d = (const float*)d_in[1];
    const float* W1  = (const float*)d_in[2];
    const float* b1  = (const float*)d_in[3];
    const float* W2  = (const float*)d_in[4];
    const float* b2  = (const float*)d_in[5];
    const float* Wo  = (const float*)d_in[6];
    // d_in[7] = bo: shifts T0.mean and every LSE equally -> cancels; omitted.
    float* out   = (float*)d_out;

    unsigned short* Aph = (unsigned short*)d_ws;   // 65536 fp16 (128 KB), frag-order
    unsigned short* Bph = Aph + NN * 64;           // 65536 fp16 (128 KB), frag-order
    uint4* W2h   = (uint4*)(Bph + NN * 64);        // 512 uint4 (8 KB)
    float* Crow  = (float*)(W2h + 512);            // 1024 fp32 (plain-stored by main)

    prep_kernel<<<514, 256, 0, stream>>>(z_c, z_d, W1, b1, W2, Aph, Bph, W2h);
    main_kernel<<<1024, 256, 0, stream>>>(Aph, Bph, W2h, b2, Wo, Crow);
    combine_finish<<<1, 1024, 0, stream>>>(Crow, out);
}

// Round 6
// 84.570 us; speedup vs baseline: 1.7636x; 1.0234x over previous
//
#include <hip/hip_runtime.h>
#include <hip/hip_fp16.h>
#include <math.h>

#define NN 1024

typedef _Float16 half8 __attribute__((ext_vector_type(8)));
typedef float f32x4 __attribute__((ext_vector_type(4)));

union H8U { uint4 u; half8 h; };

__device__ __forceinline__ unsigned short h_bits(float x) {
    _Float16 h = (_Float16)x;          // RNE
    unsigned short b;
    __builtin_memcpy(&b, &h, 2);
    return b;
}

// ---- prep: blocks [0,512): A' = z_c@W1c + b1 -> fp16 frag-order Aph;
//            B = z_d@W1d -> fp16 frag-order Bph.
//            blocks [512,514): W2 -> fp16 MFMA frag layout W2h.
__global__ void prep_kernel(const float* __restrict__ z_c, const float* __restrict__ z_d,
                            const float* __restrict__ W1, const float* __restrict__ b1,
                            const float* __restrict__ W2,
                            unsigned short* __restrict__ Aph,
                            unsigned short* __restrict__ Bph,
                            uint4* __restrict__ W2h) {
    if (blockIdx.x < 512) {
        int t = blockIdx.x * 256 + threadIdx.x;
        int sel = t >> 16;            // 0 -> A', 1 -> B
        int idx = t & 0xffff;
        int n = idx >> 6, h = idx & 63;
        const float* z = (sel ? z_d : z_c) + n * 64;
        const float* w = W1 + (sel ? 4096 : 0) + h;   // W1 (128,64) row-major
        float a0 = sel ? 0.f : b1[h], a1 = 0.f;
        #pragma unroll
        for (int k = 0; k < 64; k += 2) {
            a0 = fmaf(z[k],     w[k * 64],       a0);
            a1 = fmaf(z[k + 1], w[(k + 1) * 64], a1);
        }
        unsigned short val = h_bits(a0 + a1);   // fp32-exact matmul, one RNE to fp16
        int s = h >> 5, q = (h >> 3) & 3, e = h & 7;
        if (sel) {
            Bph[n * 64 + q * 16 + s * 8 + e] = val;
        } else {
            Aph[(n >> 4) * 1024 + (q * 16 + (n & 15)) * 16 + s * 8 + e] = val;
        }
    } else {
        int tt = (blockIdx.x - 512) * 256 + threadIdx.x;   // 0..511
        int f = tt >> 6, lane = tt & 63;                   // f = s*4 + t, 8 frags
        int s = f >> 2, t4 = f & 3, q = lane >> 4, l15 = lane & 15;
        int n = t4 * 16 + l15;
        unsigned w4[4];
        #pragma unroll
        for (int p = 0; p < 4; ++p) {
            int k = s * 32 + q * 8 + 2 * p;
            unsigned lo = h_bits(W2[k * 64 + n]);
            unsigned hi = h_bits(W2[(k + 1) * 64 + n]);
            w4[p] = lo | (hi << 16);
        }
        W2h[f * 64 + lane] = make_uint4(w4[0], w4[1], w4[2], w4[3]);
    }
}

// ---- main: 1024 blocks x 256 thr; block = row i, each wave 16 j-tiles of 16.
// R6: TILE-ORDER ROTATION (rot = blockIdx & 15) to break the all-blocks-lockstep
// L2 hotspot. Theory: every block read the identical Aph stream in identical
// order -> at any instant all ~128 co-resident waves/XCD hit the SAME ~1KB tile
// -> few L2 banks active -> effective L2 BW collapses (main ~19us vs ~4us
// throughput floor). R5's depth-2 prefetch (latency fix) was NULL, consistent
// with a bandwidth hotspot, not latency. Rotation gives 16 distinct tiles in
// flight across CUs; co-resident blocks on one CU (b, b+256: 256==0 mod 16)
// share rotation -> L1 reuse preserved. Only the order of summing 16 positive
// exp terms changes -> absmax ~1e-6 (threshold 6.5e-4).
// R3 POST-MORTEM stands: any register-state growth spills (325MB scratch). The
// inline per-tile epilogue (no psum[8]) keeps the footprint in the proven range.
// R4 POST-MORTEM: hipLaunchCooperativeKernel fails SILENTLY under graph capture.
// R1 POST-MORTEM: grid-scale same-address atomics ~+12us steady. Plain stores.
// __launch_bounds__(256, 4) is LOAD-BEARING. Do not raise.
__global__ void __launch_bounds__(256, 4)
main_kernel(const unsigned short* __restrict__ Aph, const unsigned short* __restrict__ Bph,
            const uint4* __restrict__ W2h,
            const float* __restrict__ b2, const float* __restrict__ Wo,
            float* __restrict__ Crow) {
    const int i    = blockIdx.x;
    const int rot  = blockIdx.x & 15;
    const int tid  = threadIdx.x;
    const int lane = tid & 63;
    const int wave = tid >> 6;
    const int l15  = lane & 15;
    const int q    = lane >> 4;

    __shared__ uint4 sW[512];      // W2 frag bits, 8 KB
    __shared__ float sb2[64];      // b2, 256 B
    __shared__ float sWo[64];      // Wo, 256 B
    __shared__ float sS[4];        // per-wave exp-sum partials
    __shared__ float sT0;          // diagonal T1[i,i] = T0[i]

    // cooperative stage: 2 x 16B VMEM per thread + tiny b2/Wo copy
    sW[tid]       = W2h[tid];
    sW[tid + 256] = W2h[tid + 256];
    if (tid < 64)                  sb2[tid]      = b2[tid];
    else if (tid < 128)            sWo[tid - 64] = Wo[tid - 64];
    __syncthreads();

    // W2 fragments from LDS: 8 ds_read_b128, lane-contiguous (conflict-free)
    half8 W[2][4];   // [s][t]
    #pragma unroll
    for (int f = 0; f < 8; ++f) {
        H8U u; u.u = sW[f * 64 + lane];
        W[f >> 2][f & 3] = u.h;
    }

    // B_i per-lane slice (fp16 frag order): 2 dwordx4 = 16 halves, k = s*32+q*8+e
    H8U cb0, cb1;
    {
        const uint4* bp = (const uint4*)(Bph + i * 64 + q * 16);
        cb0.u = bp[0];
        cb1.u = bp[1];
    }

    // b2 folded into acc init; Wo per-lane, element (t,r) is h = t*16 + q*4 + r
    f32x4 b2v[4];
    float wov[4][4];
    #pragma unroll
    for (int t = 0; t < 4; ++t) {
        float4 bt = *(const float4*)(sb2 + t * 16 + q * 4);
        float4 wt = *(const float4*)(sWo + t * 16 + q * 4);
        b2v[t] = (f32x4){bt.x, bt.y, bt.z, bt.w};
        wov[t][0] = wt.x; wov[t][1] = wt.y; wov[t][2] = wt.z; wov[t][3] = wt.w;
    }

    const half8 zero = {0, 0, 0, 0, 0, 0, 0, 0};
    float sacc = 0.f;

    // Wave's 16 tiles; physical tile for logical step t is ((t+rot)&15).
    const unsigned short* ap = Aph + (wave * 16) * 1024 + lane * 16;

    // Prologue: logical tiles 0 and 1 in flight.
    H8U xa0, xa1, xb0, xb1;
    {
        const uint4* p0 = (const uint4*)(ap + ((0 + rot) & 15) * 1024);
        xa0.u = p0[0];
        xa1.u = p0[1];
        const uint4* p1 = (const uint4*)(ap + ((1 + rot) & 15) * 1024);
        xb0.u = p1[0];
        xb1.u = p1[1];
    }

    #pragma unroll
    for (int t = 0; t < 16; t += 2) {
        // ---- even step t: consume xa (tile (t+rot)&15), refill with t+2
        {
            half8 a0 = __builtin_elementwise_max(xa0.h + cb0.h, zero);   // k 0..31
            half8 a1 = __builtin_elementwise_max(xa1.h + cb1.h, zero);   // k 32..63
            if (t + 2 < 16) {
                const uint4* nx = (const uint4*)(ap + ((t + 2 + rot) & 15) * 1024);
                xa0.u = nx[0];
                xa1.u = nx[1];
            }

            f32x4 acc[4];
            #pragma unroll
            for (int u = 0; u < 4; ++u) acc[u] = b2v[u];
            #pragma unroll
            for (int u = 0; u < 4; ++u) {
                acc[u] = __builtin_amdgcn_mfma_f32_16x16x32_f16(W[0][u], a0, acc[u], 0, 0, 0);
                acc[u] = __builtin_amdgcn_mfma_f32_16x16x32_f16(W[1][u], a1, acc[u], 0, 0, 0);
            }

            float p0 = 0.f, p1 = 0.f, p2 = 0.f, p3 = 0.f;
            #pragma unroll
            for (int u = 0; u < 4; ++u) {
                p0 = fmaf(fmaxf(acc[u][0], 0.f), wov[u][0], p0);
                p1 = fmaf(fmaxf(acc[u][1], 0.f), wov[u][1], p1);
                p2 = fmaf(fmaxf(acc[u][2], 0.f), wov[u][2], p2);
                p3 = fmaf(fmaxf(acc[u][3], 0.f), wov[u][3], p3);
            }
            float ps = (p0 + p1) + (p2 + p3);
            ps += __shfl_xor(ps, 16);
            ps += __shfl_xor(ps, 32);   // T1[j], replicated over the 4 q-groups
            const int j = (wave * 16 + ((t + rot) & 15)) * 16 + l15;
            if (j == i && q == 0) sT0 = ps;   // diagonal: exactly one writer
            sacc += __expf(ps);
        }
        // ---- odd step t+1: consume xb (tile (t+1+rot)&15), refill with t+3
        {
            half8 a0 = __builtin_elementwise_max(xb0.h + cb0.h, zero);
            half8 a1 = __builtin_elementwise_max(xb1.h + cb1.h, zero);
            if (t + 3 < 16) {
                const uint4* nx = (const uint4*)(ap + ((t + 3 + rot) & 15) * 1024);
                xb0.u = nx[0];
                xb1.u = nx[1];
            }

            f32x4 acc[4];
            #pragma unroll
            for (int u = 0; u < 4; ++u) acc[u] = b2v[u];
            #pragma unroll
            for (int u = 0; u < 4; ++u) {
                acc[u] = __builtin_amdgcn_mfma_f32_16x16x32_f16(W[0][u], a0, acc[u], 0, 0, 0);
                acc[u] = __builtin_amdgcn_mfma_f32_16x16x32_f16(W[1][u], a1, acc[u], 0, 0, 0);
            }

            float p0 = 0.f, p1 = 0.f, p2 = 0.f, p3 = 0.f;
            #pragma unroll
            for (int u = 0; u < 4; ++u) {
                p0 = fmaf(fmaxf(acc[u][0], 0.f), wov[u][0], p0);
                p1 = fmaf(fmaxf(acc[u][1], 0.f), wov[u][1], p1);
                p2 = fmaf(fmaxf(acc[u][2], 0.f), wov[u][2], p2);
                p3 = fmaf(fmaxf(acc[u][3], 0.f), wov[u][3], p3);
            }
            float ps = (p0 + p1) + (p2 + p3);
            ps += __shfl_xor(ps, 16);
            ps += __shfl_xor(ps, 32);
            const int j = (wave * 16 + ((t + 1 + rot) & 15)) * 16 + l15;
            if (j == i && q == 0) sT0 = ps;
            sacc += __expf(ps);
        }
    }

    // reduce over l15 only (q-groups are exact replicas -> exact sum)
    sacc += __shfl_xor(sacc, 1);
    sacc += __shfl_xor(sacc, 2);
    sacc += __shfl_xor(sacc, 4);
    sacc += __shfl_xor(sacc, 8);
    if (lane == 0) sS[wave] = sacc;
    __syncthreads();
    if (tid == 0) {
        float S = (sS[0] + sS[1]) + (sS[2] + sS[3]);   // whole row in this block
        Crow[i] = sT0 - logf(S);   // per-row logf: 1024-way parallel
    }
}

// ---- combine: 1 block x 1024 thr. bound = mean(Crow) + ln N
__global__ void __launch_bounds__(1024)
combine_finish(const float* __restrict__ Crow, float* __restrict__ out) {
    float c = Crow[threadIdx.x];
    #pragma unroll
    for (int off = 1; off < 64; off <<= 1) c += __shfl_xor(c, off);
    __shared__ float sc[16];
    int w = threadIdx.x >> 6;
    if ((threadIdx.x & 63) == 0) sc[w] = c;
    __syncthreads();
    if (threadIdx.x == 0) {
        float C = 0.f;
        #pragma unroll
        for (int k = 0; k < 16; ++k) C += sc[k];
        out[0] = C * (1.0f / 1024.0f) + 6.9314718055994531f;   // + ln 1024
    }
}

extern "C" void kernel_launch(void* const* d_in, const int* in_sizes, int n_in,
                              void* d_out, int out_size, void* d_ws, size_t ws_size,
                              hipStream_t stream) {
    const float* z_c = (const float*)d_in[0];
    const float* z_d = (const float*)d_in[1];
    const float* W1  = (const float*)d_in[2];
    const float* b1  = (const float*)d_in[3];
    const float* W2  = (const float*)d_in[4];
    const float* b2  = (const float*)d_in[5];
    const float* Wo  = (const float*)d_in[6];
    // d_in[7] = bo: shifts T0.mean and every LSE equally -> cancels; omitted.
    float* out   = (float*)d_out;

    unsigned short* Aph = (unsigned short*)d_ws;   // 65536 fp16 (128 KB), frag-order
    unsigned short* Bph = Aph + NN * 64;           // 65536 fp16 (128 KB), frag-order
    uint4* W2h   = (uint4*)(Bph + NN * 64);        // 512 uint4 (8 KB)
    float* Crow  = (float*)(W2h + 512);            // 1024 fp32 (plain-stored by main)

    prep_kernel<<<514, 256, 0, stream>>>(z_c, z_d, W1, b1, W2, Aph, Bph, W2h);
    main_kernel<<<1024, 256, 0, stream>>>(Aph, Bph, W2h, b2, Wo, Crow);
    combine_finish<<<1, 1024, 0, stream>>>(Crow, out);
}